// Round 7
// baseline (919.728 us; speedup 1.0000x reference)
//
#include <hip/hip_runtime.h>
#include <math.h>

#define F_FILT   40
#define K_GABOR  401
#define HOP      160
#define T_LEN    160000
#define B_BATCH  8
#define EPS_PCENF 1e-6f
#define EPS_INF   1e-5f

#define THREADS  320
#define NWAVES   5
#define RT       10
#define TILE     3200        // THREADS*RT
#define TPC      5           // payload tiles per chunk/block
#define CHUNKS   10          // T_LEN / (TILE*TPC)
#define NPT      20          // pooled outputs per tile
#define NPOOL_BLK 100        // TPC*NPT
#define KT       416         // padded tap count (401 + unroll-16 overrun)
#define KP       208         // pool-kernel f16 pairs (zero padded)
#define HALO     400         // K_GABOR-1 samples
#define XSF      3648        // f32 x tile + halo + pad (max read 3621)
#define HALOP    200         // comp halo pairs
#define TILEP    1600        // comp tile pairs
#define RINGP    1800        // comp ring pairs

typedef float  f2  __attribute__((ext_vector_type(2)));
typedef _Float16 h2_t __attribute__((ext_vector_type(2)));

__device__ __forceinline__ float fdot2(h2_t a, h2_t b, float c) {
    return __builtin_amdgcn_fdot2(a, b, c, false);
}
__device__ __forceinline__ unsigned pk2(float a, float b) {
    return __builtin_bit_cast(unsigned, __builtin_amdgcn_cvt_pkrtz(a, b));
}
__device__ __forceinline__ h2_t bch(unsigned u) {
    return __builtin_bit_cast(h2_t, u);
}

// ---------- setup: per-filter f32 gabor pairs + f16 pool kernel into d_ws ----------
__global__ __launch_bounds__(256) void leaf_weights(
    const float* __restrict__ eta_g, const float* __restrict__ sigma_g,
    const float* __restrict__ bw_g,
    f2* __restrict__ wtab, unsigned* __restrict__ pktab)
{
    const int f = blockIdx.x;
    const float eta   = eta_g[f];
    const float sigma = sigma_g[f];
    const float bw    = fminf(fmaxf(bw_g[f], 2.0f / 401.0f), 0.5f);
    const float envc  = 0.3989422804014327f / sigma;
    const float den   = bw * 0.5f * 400.0f;

    for (int k = threadIdx.x; k < KT; k += 256) {
        f2 w = {0.f, 0.f};
        if (k < K_GABOR) {
            float t = (float)(k - 200);
            float z = t / sigma;
            float e = envc * expf(-0.5f * z * z);
            float ph = eta * t;
            w.x = e * cosf(ph);
            w.y = e * sinf(ph);
        }
        wtab[f * KT + k] = w;
    }
    for (int i = threadIdx.x; i < KP; i += 256) {
        float pp[2];
        for (int j = 0; j < 2; ++j) {
            int k = 2 * i + j;
            float pv = 0.f;
            if (k < K_GABOR) {
                float tp = (float)(k - 201);
                float d = tp / den;
                pv = expf(-0.5f * d * d);
            }
            pp[j] = pv;
        }
        pktab[f * KP + i] = pk2(pp[0], pp[1]);
    }
}

// ---------- main fused kernel: one block = (b, f, chunk of 5 tiles) ----------
__global__ __launch_bounds__(THREADS) void leaf_main(
    const float* __restrict__ x,
    const float* __restrict__ sigma_g,
    const float* __restrict__ bias_g,
    const float* __restrict__ ema_g,
    const float* __restrict__ alpha_g,
    const float* __restrict__ delta_g,
    const float* __restrict__ root_g,
    const f2* __restrict__ wtab,
    const unsigned* __restrict__ pktab,
    float* __restrict__ out)
{
    __shared__ float    xs[XSF];       // x as f32 (halo + tile + pad)
    __shared__ unsigned ringl[RINGP];  // comp as f16 pairs
    __shared__ unsigned pkpl[KP];      // pool kernel f16 pairs
    __shared__ float pooled[NPOOL_BLK];
    __shared__ float waveV[NWAVES], cwArr[NWAVES];
    __shared__ float carryLds, p0Lds;

    const int blk   = blockIdx.x;
    const int f     = blk % F_FILT;               // f fastest: mixes heavy/light
    const int b     = (blk / F_FILT) % B_BATCH;
    const int chunk = blk / (F_FILT * B_BATCH);
    const int bf    = b * F_FILT + f;
    const int tid  = threadIdx.x;
    const int lane = tid & 63;
    const int wave = tid >> 6;

    const float sw    = fminf(fmaxf(ema_g[f], 0.0f), 1.0f);
    const float a     = 1.0f - sw;
    const float alpha = fminf(alpha_g[f], 1.0f);
    const float inv_r = 1.0f / fmaxf(root_g[f], 1.0f);
    const float dlt   = delta_g[f];
    const float dpow  = powf(dlt, inv_r);

    // truncated support: taps |k-200| <= R = 4.5*sigma, 16-aligned start
    const float sigma = sigma_g[f];
    const int R    = min(200, (int)ceilf(4.5f * sigma));
    const int S16  = (200 - R) & ~15;
    const int nt16 = ((200 + R - S16) >> 4) + 1;   // <= 26
    const f2* __restrict__ wt = wtab + (size_t)f * KT + S16;

    // init LDS
    for (int i = tid; i < XSF;   i += THREADS) xs[i] = 0.f;
    for (int i = tid; i < RINGP; i += THREADS) ringl[i] = 0u;
    for (int i = tid; i < NPOOL_BLK; i += THREADS) pooled[i] = 0.f;
    if (tid < KP) pkpl[tid] = pktab[f * KP + tid];
    if (tid == 0) carryLds = 0.f;

    // scan factors: A1 = a^RT
    const float a2 = a * a, a4 = a2 * a2, a8 = a4 * a4;
    const float A1  = a8 * a2;          // a^10
    const float A2  = A1 * A1, A4 = A2 * A2, A8 = A4 * A4;
    const float A16 = A8 * A8, A32 = A16 * A16, A64 = A32 * A32;
    float Al = 1.0f;
    if (lane & 1)  Al *= A1;
    if (lane & 2)  Al *= A2;
    if (lane & 4)  Al *= A4;
    if (lane & 8)  Al *= A8;
    if (lane & 16) Al *= A16;
    if (lane & 32) Al *= A32;

    const float* xb = x + (size_t)b * T_LEN;
    const int tile0 = chunk * TPC;
    const int itStart = (chunk == 0) ? 0 : -1;    // warm-up tile for chunk>0
    const int r0 = RT * tid;
    const unsigned P0 = 5u * (unsigned)tid;       // ring pair base
    const int base = r0 + S16;

    for (int it = itStart; it < TPC; ++it) {
        const int tileT0 = (tile0 + it) * TILE;
        __syncthreads();
        // slide previous tails (x halo f32: 400 > 320 threads -> two passes)
        const bool doSlide = (it != itStart);
        float tx0 = 0.f, tx1 = 0.f; unsigned tr = 0u;
        if (doSlide) {
            tx0 = xs[TILE + tid];
            if (tid < HALO - THREADS) tx1 = xs[TILE + THREADS + tid];
            if (tid < HALOP) tr = ringl[TILEP + tid];
        }
        float2 sv[5];
        const float2* src = (const float2*)(xb + tileT0);
#pragma unroll
        for (int t = 0; t < 5; ++t) sv[t] = src[tid + 320 * t];
        __syncthreads();
        if (doSlide) {
            xs[tid] = tx0;
            if (tid < HALO - THREADS) xs[THREADS + tid] = tx1;
            if (tid < HALOP) ringl[tid] = tr;
        }
#pragma unroll
        for (int t = 0; t < 5; ++t) {
            xs[HALO + 2 * (tid + 320 * t)]     = sv[t].x;
            xs[HALO + 2 * (tid + 320 * t) + 1] = sv[t].y;
        }
        __syncthreads();

        // ---- Gabor conv via v_pk_fma_f32: 10 outputs, 16-slot rotating window ----
        f2 acc[RT];
#pragma unroll
        for (int r = 0; r < RT; ++r) acc[r] = (f2){0.f, 0.f};
        float W[16];
#pragma unroll
        for (int j = 0; j < 16; ++j) W[j] = xs[base + j];

        for (int i16 = 0; i16 < nt16; ++i16) {
            const f2* wv = wt + i16 * 16;
            const int nb = base + i16 * 16 + 16;
#pragma unroll
            for (int u = 0; u < 16; ++u) {
                const f2 w = wv[u];                   // uniform -> s_load
#pragma unroll
                for (int r = 0; r < RT; ++r) {
                    const float xv = W[(u + r) & 15];
                    acc[r] = __builtin_elementwise_fma(w, (f2){xv, xv}, acc[r]);
                }
                W[u] = xs[nb + u];
            }
        }

        // ---- power + thread-local EMA ----
        float p[RT], up[RT];
        float uu = 0.f;
#pragma unroll
        for (int r = 0; r < RT; ++r) {
            p[r] = fmaf(acc[r].x, acc[r].x, acc[r].y * acc[r].y);
            uu = fmaf(a, uu, sw * p[r]);
            up[r] = uu;
        }
        if (chunk == 0 && it == 0 && tid == 0) p0Lds = p[0];

        // ---- EMA Kogge-Stone scan over threads ----
        float v = uu;
        {
            float tv;
            tv = __shfl_up(v, 1);  if (lane >= 1)  v = fmaf(A1,  tv, v);
            tv = __shfl_up(v, 2);  if (lane >= 2)  v = fmaf(A2,  tv, v);
            tv = __shfl_up(v, 4);  if (lane >= 4)  v = fmaf(A4,  tv, v);
            tv = __shfl_up(v, 8);  if (lane >= 8)  v = fmaf(A8,  tv, v);
            tv = __shfl_up(v, 16); if (lane >= 16) v = fmaf(A16, tv, v);
            tv = __shfl_up(v, 32); if (lane >= 32) v = fmaf(A32, tv, v);
        }
        if (lane == 63) waveV[wave] = v;
        __syncthreads();
        if (tid == 0) {
            float c = (chunk == 0 && it == 0) ? p0Lds : carryLds;
#pragma unroll
            for (int w = 0; w < NWAVES; ++w) { cwArr[w] = c; c = fmaf(A64, c, waveV[w]); }
            carryLds = c;
        }
        __syncthreads();
        float cin;
        {
            const float cw = cwArr[wave];
            float ve = __shfl_up(v, 1);
            if (lane == 0) ve = 0.f;
            cin = fmaf(Al, cw, ve);
        }

        // ---- PCEN + f16 ring writes ----
        float apr = a;
#pragma unroll
        for (int j = 0; j < 5; ++j) {
            const float e0 = fmaf(apr, cin, up[2 * j]);     apr *= a;
            const float e1 = fmaf(apr, cin, up[2 * j + 1]); apr *= a;
            const float q0 = fmaf(p[2 * j],     exp2f(-alpha * log2f(EPS_PCENF + e0)), dlt);
            const float q1 = fmaf(p[2 * j + 1], exp2f(-alpha * log2f(EPS_PCENF + e1)), dlt);
            const float c0 = exp2f(inv_r * log2f(q0)) - dpow;
            const float c1 = exp2f(inv_r * log2f(q1)) - dpow;
            ringl[HALOP + P0 + j] = pk2(c0, c1);
        }
        __syncthreads();

        // ---- pooling via dot2: 20 outputs x 16 lanes ----
        if (it >= 0) {
            const int o = tid >> 4, l = tid & 15;
            float part = 0.f;
#pragma unroll
            for (int t = 0; t < 13; ++t) {
                const int kpp = l + 16 * t;   // 0..207, pkpl zero-padded
                part = fdot2(bch(ringl[o * 80 + kpp]), bch(pkpl[kpp]), part);
            }
            part += __shfl_xor(part, 1, 16);
            part += __shfl_xor(part, 2, 16);
            part += __shfl_xor(part, 4, 16);
            part += __shfl_xor(part, 8, 16);
            if (l == 0) pooled[it * NPT + o] += part;
        }
    }
    __syncthreads();

    const float bias = bias_g[f];
    for (int i = tid; i < NPOOL_BLK; i += THREADS)
        out[(size_t)bf * 1000 + (size_t)(tile0 * NPT) + i] = pooled[i] + bias;
}

// ---------- instance norm over 1000 frames, in place ----------
__global__ __launch_bounds__(256) void leaf_norm(float* __restrict__ out)
{
    const int bf = blockIdx.x;
    float* p = out + (size_t)bf * 1000;
    __shared__ float buf[1000];
    __shared__ float red[4];
    const int tid = threadIdx.x;
    const int lane = tid & 63, wave = tid >> 6;

    float sum = 0.0f;
    for (int i = tid; i < 1000; i += 256) { float v = p[i]; buf[i] = v; sum += v; }
    for (int m = 1; m < 64; m <<= 1) sum += __shfl_xor(sum, m);
    if (lane == 0) red[wave] = sum;
    __syncthreads();
    const float mean = (red[0] + red[1] + red[2] + red[3]) * 0.001f;

    float vs = 0.0f;
    for (int i = tid; i < 1000; i += 256) { float d = buf[i] - mean; vs += d * d; }
    for (int m = 1; m < 64; m <<= 1) vs += __shfl_xor(vs, m);
    __syncthreads();
    if (lane == 0) red[wave] = vs;
    __syncthreads();
    const float var   = (red[0] + red[1] + red[2] + red[3]) * 0.001f;
    const float scale = rsqrtf(var + EPS_INF);
    for (int i = tid; i < 1000; i += 256) p[i] = (buf[i] - mean) * scale;
}

extern "C" void kernel_launch(void* const* d_in, const int* in_sizes, int n_in,
                              void* d_out, int out_size, void* d_ws, size_t ws_size,
                              hipStream_t stream)
{
    const float* x     = (const float*)d_in[0];
    const float* eta   = (const float*)d_in[1];
    const float* sigma = (const float*)d_in[2];
    const float* bw    = (const float*)d_in[3];
    const float* bias  = (const float*)d_in[4];
    const float* emaw  = (const float*)d_in[5];
    const float* alpha = (const float*)d_in[6];
    const float* delta = (const float*)d_in[7];
    const float* root  = (const float*)d_in[8];
    float* outp = (float*)d_out;

    f2*       wtab  = (f2*)d_ws;                                      // 40*416*8 B
    unsigned* pktab = (unsigned*)((char*)d_ws + (size_t)F_FILT * KT * sizeof(f2));

    hipLaunchKernelGGL(leaf_weights, dim3(F_FILT), dim3(256), 0, stream,
                       eta, sigma, bw, wtab, pktab);
    hipLaunchKernelGGL(leaf_main, dim3(B_BATCH * F_FILT * CHUNKS), dim3(THREADS), 0, stream,
                       x, sigma, bias, emaw, alpha, delta, root, wtab, pktab, outp);
    hipLaunchKernelGGL(leaf_norm, dim3(B_BATCH * F_FILT), dim3(256), 0, stream, outp);
}